// Round 8
// baseline (1688.081 us; speedup 1.0000x reference)
//
#include <hip/hip_runtime.h>

#define USH unsigned short

__device__ inline float bf2f(USH u){ return __uint_as_float(((unsigned)u)<<16); }
__device__ inline USH f2bf(float f){
  unsigned u = __float_as_uint(f);
  return (USH)((u + 0x7FFFu + ((u>>16)&1u))>>16);
}

typedef __attribute__((ext_vector_type(8))) short bf16x8;
typedef __attribute__((ext_vector_type(4))) float f32x4;

__device__ inline void gll16(const USH* g, USH* l){
  __builtin_amdgcn_global_load_lds((const __attribute__((address_space(1))) void*)g,
                                   (__attribute__((address_space(3))) void*)l, 16, 0, 0);
}

// ------------------------------------------------------------------
// conv1: x(512,28,28,1) f32 -> h(512,20,20,256) bf16, valid 9x9 s1, relu
__global__ __launch_bounds__(256) void conv1_kernel(
    const float* __restrict__ x, const float* __restrict__ k1,
    const float* __restrict__ b1, USH* __restrict__ h)
{
  int b = blockIdx.x;
  int y0 = blockIdx.y * 4;
  int c = threadIdx.x;
  __shared__ float xs[784];
  for (int i = c; i < 784; i += 256) xs[i] = x[b*784 + i];
  __syncthreads();
  float bias = b1[c];
  for (int y = y0; y < y0 + 4; ++y) {
    float acc[20];
#pragma unroll
    for (int i = 0; i < 20; ++i) acc[i] = bias;
    for (int dy = 0; dy < 9; ++dy) {
      float xr[28];
#pragma unroll
      for (int i = 0; i < 28; ++i) xr[i] = xs[(y+dy)*28 + i];
#pragma unroll
      for (int dx = 0; dx < 9; ++dx) {
        float wv = k1[(dy*9+dx)*256 + c];
#pragma unroll
        for (int xx = 0; xx < 20; ++xx) acc[xx] += xr[dx+xx]*wv;
      }
    }
#pragma unroll
    for (int xx = 0; xx < 20; ++xx) {
      float v = acc[xx] > 0.f ? acc[xx] : 0.f;
      h[((b*20+y)*20+xx)*256 + c] = f2bf(v);
    }
  }
}

// ------------------------------------------------------------------
// k2 (20736,256) f32 -> k2T (256,20736) bf16
__global__ __launch_bounds__(256) void tr_k2(const float* __restrict__ k2, USH* __restrict__ k2T)
{
  __shared__ float tile[32][33];
  int kb = blockIdx.x*32, nb = blockIdx.y*32;
  int tx = threadIdx.x & 31, ty = threadIdx.x >> 5;
#pragma unroll
  for (int r = 0; r < 4; ++r) {
    int k = kb + ty + r*8;
    tile[ty + r*8][tx] = k2[(size_t)k*256 + nb + tx];
  }
  __syncthreads();
#pragma unroll
  for (int r = 0; r < 4; ++r) {
    int n = nb + ty + r*8;
    k2T[(size_t)n*20736 + kb + tx] = f2bf(tile[tx][ty + r*8]);
  }
}

// ------------------------------------------------------------------
// conv2 implicit GEMM: bf16 MFMA 16x16x32, BM=128 BN=64 BK=64, 4 waves,
// 2-buffer LDS + XOR swizzle, split-K x2 (blockIdx.z), f32 partials.
__global__ __launch_bounds__(256) void conv2_mfma(
    const USH* __restrict__ h, const USH* __restrict__ k2T,
    float* __restrict__ up)
{
  __shared__ __align__(16) USH Asm[2][128*64];
  __shared__ __align__(16) USH Bsm[2][64*64];
  int t = threadIdx.x;
  int mb = blockIdx.x, nb = blockIdx.y, ksl = blockIdx.z;

  int sg = (((t&7) ^ ((t>>3)&7)) << 3);   // pre-swizzled source group

  int arow_off[4];
#pragma unroll
  for (int i = 0; i < 4; ++i) {
    int row = (t>>3) + i*32;
    int m = mb*128 + row;
    int bb = m/36, r = m - bb*36;
    int oy = r/6, ox = r - oy*6;
    arow_off[i] = bb*102400 + oy*10240 + ox*512 + sg;
  }
  int brow_off[2];
#pragma unroll
  for (int i = 0; i < 2; ++i) {
    int nl = (t>>3) + i*32;
    brow_off[i] = (nb*64 + nl)*20736 + sg;
  }

  int lane = t & 63;
  int wave = t >> 6;
  int wm = (wave>>1)*64, wn = (wave&1)*32;
  int fr = lane & 15, fq = lane >> 4;

  f32x4 acc[4][2];
#pragma unroll
  for (int i = 0; i < 4; ++i)
#pragma unroll
    for (int j = 0; j < 2; ++j)
#pragma unroll
      for (int r = 0; r < 4; ++r) acc[i][j][r] = 0.f;

  int rg0 = (((0*4 + fq) ^ (fr&7)) << 3);
  int rg1 = (((1*4 + fq) ^ (fr&7)) << 3);

#define STAGE(buf, kt) do {                                            \
    int j_ = (kt) >> 2;                                                \
    int cin0_ = ((kt) & 3) << 6;                                       \
    int dy_ = j_/9, dx_ = j_ - dy_*9;                                  \
    int koff_ = (dy_*20 + dx_)*256 + cin0_;                            \
    USH* Ad_ = &Asm[buf][(t>>6)*512];                                  \
    USH* Bd_ = &Bsm[buf][(t>>6)*512];                                  \
    _Pragma("unroll")                                                  \
    for (int i_ = 0; i_ < 4; ++i_) gll16(h + arow_off[i_] + koff_, Ad_ + i_*2048); \
    _Pragma("unroll")                                                  \
    for (int i_ = 0; i_ < 2; ++i_) gll16(k2T + brow_off[i_] + (kt)*64, Bd_ + i_*2048); \
  } while(0)

  const int k0 = ksl*162, kend = k0 + 162;
  STAGE(0, k0);
  __syncthreads();

  int cur = 0;
  for (int kt = k0; kt < kend; ++kt) {
    if (kt + 1 < kend) STAGE(cur^1, kt+1);

    bf16x8 af[4][2], bg[2][2];
#pragma unroll
    for (int mf = 0; mf < 4; ++mf) {
      af[mf][0] = *(const bf16x8*)&Asm[cur][(wm + mf*16 + fr)*64 + rg0];
      af[mf][1] = *(const bf16x8*)&Asm[cur][(wm + mf*16 + fr)*64 + rg1];
    }
#pragma unroll
    for (int nf = 0; nf < 2; ++nf) {
      bg[nf][0] = *(const bf16x8*)&Bsm[cur][(wn + nf*16 + fr)*64 + rg0];
      bg[nf][1] = *(const bf16x8*)&Bsm[cur][(wn + nf*16 + fr)*64 + rg1];
    }
#pragma unroll
    for (int mf = 0; mf < 4; ++mf)
#pragma unroll
      for (int nf = 0; nf < 2; ++nf) {
        acc[mf][nf] = __builtin_amdgcn_mfma_f32_16x16x32_bf16(af[mf][0], bg[nf][0], acc[mf][nf], 0,0,0);
        acc[mf][nf] = __builtin_amdgcn_mfma_f32_16x16x32_bf16(af[mf][1], bg[nf][1], acc[mf][nf], 0,0,0);
      }
    __syncthreads();
    cur ^= 1;
  }
#undef STAGE

  float* dst = up + (size_t)ksl*4718592;
#pragma unroll
  for (int mf = 0; mf < 4; ++mf)
#pragma unroll
    for (int nf = 0; nf < 2; ++nf) {
      int n = nb*64 + wn + nf*16 + fr;
#pragma unroll
      for (int r = 0; r < 4; ++r) {
        int m = mb*128 + wm + mf*16 + fq*4 + r;
        dst[(size_t)m*256 + n] = acc[mf][nf][r];
      }
    }
}

// ------------------------------------------------------------------
// u = up[0] + up[1] + bias  (f32x4 over 18432x256)
__global__ __launch_bounds__(256) void reduce_u(
    const float* __restrict__ up, const float* __restrict__ b2, float* __restrict__ u)
{
  int i = blockIdx.x*256 + threadIdx.x;   // quad index
  f32x4 a = *(const f32x4*)&up[(size_t)i*4];
  f32x4 b = *(const f32x4*)&up[4718592ull + (size_t)i*4];
  int n0 = (i*4) & 255;
  f32x4 o;
#pragma unroll
  for (int j = 0; j < 4; ++j) o[j] = a[j] + b[j] + b2[n0 + j];
  *(f32x4*)&u[(size_t)i*4] = o;
}

// ------------------------------------------------------------------
// Routing pass with u_hat RECOMPUTE (no 188MB u_hat buffer, no L buffer).
// Block = (16 b's, 72-n chunk). 256 thr = 16 streams x 16 lanes; lane = sector.
// Per (b,n,s): uhat[16] = w[n,s,:,:] @ u[b,n,:]  (16 d x 8 p = 32 f32x4 of w,
// loaded 2-per-d inside the unrolled d loop -- round-7's wq[8] OOB bug fixed).
// PASS 1: acc += uhat (c uniform, 0.1 applied at squash).
// PASS 2: dot=uhat.vin, softmax over s via shfl(16), acc += c*uhat.
//   (iter-3 logits = uhat.(v1+v2) algebraically, so vin=vsum reuses this.)
template<int PASS>
__global__ __launch_bounds__(256) void route_recomp(
    const float* __restrict__ u, const float* __restrict__ w,
    const float* __restrict__ vin, float* __restrict__ partR)
{
  int b0 = blockIdx.x*16, nbase = blockIdx.y*72;
  int t = threadIdx.x;
  int lane = t & 63, wv = t >> 6;
  int grp = lane >> 4, s = lane & 15;
  int stream = wv*4 + grp;            // local b
  bool act = s < 10;
  int sw = act ? s : 0;               // clamp: avoid OOB w/v reads on idle lanes
  int b = b0 + stream;

  __shared__ float u_lds[16][584];    // 584%32==8 -> streams hit distinct banks
  for (int i = t; i < 16*576; i += 256) {
    int bl = i/576, off = i - bl*576;
    u_lds[bl][off] = u[(size_t)(b0+bl)*9216 + nbase*8 + off];
  }

  float vr[16];
  if (PASS >= 2) {
    const float* vp = vin + b*160 + sw*16;
#pragma unroll
    for (int d = 0; d < 16; ++d) vr[d] = act ? vp[d] : 0.f;
  }
  float acc[16];
#pragma unroll
  for (int d = 0; d < 16; ++d) acc[d] = 0.f;
  __syncthreads();

  const float* wbase = w + (size_t)nbase*1280 + sw*128;
#pragma unroll 1
  for (int ni = 0; ni < 72; ++ni) {
    const f32x4* wp = (const f32x4*)(wbase + (size_t)ni*1280);
    f32x4 u0 = *(const f32x4*)&u_lds[stream][ni*8];
    f32x4 u1 = *(const f32x4*)&u_lds[stream][ni*8 + 4];

    float uhat[16];
#pragma unroll
    for (int d = 0; d < 16; ++d) {
      f32x4 wa = wp[2*d];
      f32x4 wb = wp[2*d + 1];
      uhat[d] = wa[0]*u0[0] + wa[1]*u0[1] + wa[2]*u0[2] + wa[3]*u0[3]
              + wb[0]*u1[0] + wb[1]*u1[1] + wb[2]*u1[2] + wb[3]*u1[3];
    }

    if (PASS == 1) {
#pragma unroll
      for (int d = 0; d < 16; ++d) acc[d] += uhat[d];
    } else {
      float dot = 0.f;
#pragma unroll
      for (int d = 0; d < 16; ++d) dot += uhat[d]*vr[d];
      float lg = act ? dot : -1e30f;
      float mx = lg;
      mx = fmaxf(mx, __shfl_xor(mx, 1, 16));
      mx = fmaxf(mx, __shfl_xor(mx, 2, 16));
      mx = fmaxf(mx, __shfl_xor(mx, 4, 16));
      mx = fmaxf(mx, __shfl_xor(mx, 8, 16));
      float e = __expf(lg - mx);
      float sum = e;
      sum += __shfl_xor(sum, 1, 16);
      sum += __shfl_xor(sum, 2, 16);
      sum += __shfl_xor(sum, 4, 16);
      sum += __shfl_xor(sum, 8, 16);
      float c = e / sum;
#pragma unroll
      for (int d = 0; d < 16; ++d) acc[d] += c*uhat[d];
    }
  }

  if (act) {
    float* pp = &partR[((size_t)blockIdx.y*512 + b)*160 + s*16];
#pragma unroll
    for (int d = 0; d < 16; ++d) pp[d] = acc[d];
  }
}

// ------------------------------------------------------------------
// squash over 16 n-chunk partials.
// PASS1: scale 0.1, vout=v1. PASS2: vout=v2, vext=v1+v2. PASS3: vout=v3, vext=out.
template<int PASS>
__global__ __launch_bounds__(192) void squash_part(const float* __restrict__ partR,
    const float* __restrict__ vprev, float* __restrict__ vout, float* __restrict__ vext)
{
  int b = blockIdx.x, t = threadIdx.x;
  if (t < 160) {
    float sv = 0.f;
#pragma unroll
    for (int nc = 0; nc < 16; ++nc) sv += partR[((size_t)nc*512 + b)*160 + t];
    if (PASS == 1) sv *= 0.1f;
    float n2 = sv*sv;
    n2 += __shfl_xor(n2, 1, 16);
    n2 += __shfl_xor(n2, 2, 16);
    n2 += __shfl_xor(n2, 4, 16);
    n2 += __shfl_xor(n2, 8, 16);
    float nrm = sqrtf(n2);
    float o = (n2/(1.f + n2)) * sv / (nrm + 1e-7f);
    vout[b*160 + t] = o;
    if (PASS == 2) vext[b*160 + t] = vprev[b*160 + t] + o;  // vsum for iter-3 logits
    if (PASS == 3) vext[b*160 + t] = o;                      // out[0:81920] = v
  }
}

// ------------------------------------------------------------------
// decoder
__global__ __launch_bounds__(512) void d1_kernel(const float* __restrict__ v3,
    const int* __restrict__ labels, const float* __restrict__ w,
    const float* __restrict__ bias, float* __restrict__ r1)
{
  int b = blockIdx.x; int j = threadIdx.x;
  int lb = labels[b];
  float acc = bias[j];
#pragma unroll
  for (int d = 0; d < 16; ++d)
    acc += v3[b*160 + lb*16 + d] * w[(lb*16 + d)*512 + j];
  r1[(size_t)b*512 + j] = acc > 0.f ? acc : 0.f;
}

__global__ __launch_bounds__(256) void d2_kernel(const float* __restrict__ a,
    const float* __restrict__ w, const float* __restrict__ bias, float* __restrict__ o)
{
  int j = blockIdx.x*256 + threadIdx.x;
  int b0 = blockIdx.y*8;
  __shared__ float as[8*512];
  for (int i = threadIdx.x; i < 8*512; i += 256) as[i] = a[(size_t)(b0 + (i>>9))*512 + (i&511)];
  __syncthreads();
  float acc[8];
  float bs = bias[j];
#pragma unroll
  for (int i = 0; i < 8; ++i) acc[i] = bs;
  for (int k = 0; k < 512; ++k) {
    float wv = w[(size_t)k*1024 + j];
#pragma unroll
    for (int i = 0; i < 8; ++i) acc[i] += as[i*512 + k]*wv;
  }
#pragma unroll
  for (int i = 0; i < 8; ++i)
    o[(size_t)(b0+i)*1024 + j] = acc[i] > 0.f ? acc[i] : 0.f;
}

__global__ __launch_bounds__(256) void d3_kernel(const float* __restrict__ a,
    const float* __restrict__ w, const float* __restrict__ bias, float* __restrict__ o)
{
  int j = blockIdx.x*256 + threadIdx.x;
  int b0 = blockIdx.y*8;
  __shared__ float as[8*1024];
  for (int i = threadIdx.x; i < 8*1024; i += 256) as[i] = a[(size_t)(b0 + (i>>10))*1024 + (i&1023)];
  __syncthreads();
  if (j < 784) {
    float acc[8];
    float bs = bias[j];
#pragma unroll
    for (int i = 0; i < 8; ++i) acc[i] = bs;
    for (int k = 0; k < 1024; ++k) {
      float wv = w[(size_t)k*784 + j];
#pragma unroll
      for (int i = 0; i < 8; ++i) acc[i] += as[i*1024 + k]*wv;
    }
#pragma unroll
    for (int i = 0; i < 8; ++i)
      o[(size_t)(b0+i)*784 + j] = 1.f/(1.f + __expf(-acc[i]));
  }
}

// ------------------------------------------------------------------
extern "C" void kernel_launch(void* const* d_in, const int* in_sizes, int n_in,
                              void* d_out, int out_size, void* d_ws, size_t ws_size,
                              hipStream_t stream)
{
  const float* x   = (const float*)d_in[0];
  const int*   lab = (const int*)  d_in[1];
  const float* k1  = (const float*)d_in[2];
  const float* b1  = (const float*)d_in[3];
  const float* k2  = (const float*)d_in[4];
  const float* b2  = (const float*)d_in[5];
  const float* w   = (const float*)d_in[6];
  const float* d1w = (const float*)d_in[7];
  const float* d1b = (const float*)d_in[8];
  const float* d2w = (const float*)d_in[9];
  const float* d2b = (const float*)d_in[10];
  const float* d3w = (const float*)d_in[11];
  const float* d3b = (const float*)d_in[12];
  float* out = (float*)d_out;

  char* ws = (char*)d_ws;
  // layout (bytes):
  //   h    [0, 104857600)          bf16 conv1 out (dead after conv2)
  //   up   [104857600, 142606336)  2x f32 conv2 partials (dead after reduce_u)
  //   u    [188743680, 207618048)
  //   k2T  [207618048, 218234880)  (dead after conv2; partR overlays: 5.24 MB)
  //   v/r  [218234880, ...)
  USH*   h     = (USH*)(ws + 0);
  float* up    = (float*)(ws + 104857600ull);
  float* u     = (float*)(ws + 188743680ull);
  USH*   k2T   = (USH*)(ws + 207618048ull);
  float* partR = (float*)(ws + 207618048ull);
  float* v1    = (float*)(ws + 218234880ull);
  float* v2    = (float*)(ws + 218562560ull);
  float* v3    = (float*)(ws + 218890240ull);
  float* vsum  = (float*)(ws + 219217920ull);
  float* r1    = (float*)(ws + 219545600ull);
  float* r2    = (float*)(ws + 220594176ull);

  conv1_kernel<<<dim3(512,5), 256, 0, stream>>>(x, k1, b1, h);
  tr_k2<<<dim3(648,8), 256, 0, stream>>>(k2, k2T);
  conv2_mfma<<<dim3(144,4,2), 256, 0, stream>>>(h, k2T, up);
  reduce_u<<<4608, 256, 0, stream>>>(up, b2, u);

  route_recomp<1><<<dim3(32,16), 256, 0, stream>>>(u, w, nullptr, partR);
  squash_part<1><<<512, 192, 0, stream>>>(partR, nullptr, v1, nullptr);
  route_recomp<2><<<dim3(32,16), 256, 0, stream>>>(u, w, v1, partR);
  squash_part<2><<<512, 192, 0, stream>>>(partR, v1, v2, vsum);
  route_recomp<2><<<dim3(32,16), 256, 0, stream>>>(u, w, vsum, partR);
  squash_part<3><<<512, 192, 0, stream>>>(partR, nullptr, v3, out);

  d1_kernel<<<512, 512, 0, stream>>>(v3, lab, d1w, d1b, r1);
  d2_kernel<<<dim3(4,64), 256, 0, stream>>>(r1, d2w, d2b, r2);
  d3_kernel<<<dim3(4,64), 256, 0, stream>>>(r2, d3w, d3b, out + 81920);
}

// Round 9
// 1229.681 us; speedup vs baseline: 1.3728x; 1.3728x over previous
//
#include <hip/hip_runtime.h>

#define USH unsigned short

__device__ inline float bf2f(USH u){ return __uint_as_float(((unsigned)u)<<16); }
__device__ inline USH f2bf(float f){
  unsigned u = __float_as_uint(f);
  return (USH)((u + 0x7FFFu + ((u>>16)&1u))>>16);
}

typedef __attribute__((ext_vector_type(8))) short bf16x8;
typedef __attribute__((ext_vector_type(4))) float f32x4;

__device__ inline void gll16(const USH* g, USH* l){
  __builtin_amdgcn_global_load_lds((const __attribute__((address_space(1))) void*)g,
                                   (__attribute__((address_space(3))) void*)l, 16, 0, 0);
}

// ------------------------------------------------------------------
// conv1: x(512,28,28,1) f32 -> h(512,20,20,256) bf16, valid 9x9 s1, relu
__global__ __launch_bounds__(256) void conv1_kernel(
    const float* __restrict__ x, const float* __restrict__ k1,
    const float* __restrict__ b1, USH* __restrict__ h)
{
  int b = blockIdx.x;
  int y0 = blockIdx.y * 4;
  int c = threadIdx.x;
  __shared__ float xs[784];
  for (int i = c; i < 784; i += 256) xs[i] = x[b*784 + i];
  __syncthreads();
  float bias = b1[c];
  for (int y = y0; y < y0 + 4; ++y) {
    float acc[20];
#pragma unroll
    for (int i = 0; i < 20; ++i) acc[i] = bias;
    for (int dy = 0; dy < 9; ++dy) {
      float xr[28];
#pragma unroll
      for (int i = 0; i < 28; ++i) xr[i] = xs[(y+dy)*28 + i];
#pragma unroll
      for (int dx = 0; dx < 9; ++dx) {
        float wv = k1[(dy*9+dx)*256 + c];
#pragma unroll
        for (int xx = 0; xx < 20; ++xx) acc[xx] += xr[dx+xx]*wv;
      }
    }
#pragma unroll
    for (int xx = 0; xx < 20; ++xx) {
      float v = acc[xx] > 0.f ? acc[xx] : 0.f;
      h[((b*20+y)*20+xx)*256 + c] = f2bf(v);
    }
  }
}

// ------------------------------------------------------------------
// k2 (20736,256) f32 -> k2T (256,20736) bf16
__global__ __launch_bounds__(256) void tr_k2(const float* __restrict__ k2, USH* __restrict__ k2T)
{
  __shared__ float tile[32][33];
  int kb = blockIdx.x*32, nb = blockIdx.y*32;
  int tx = threadIdx.x & 31, ty = threadIdx.x >> 5;
#pragma unroll
  for (int r = 0; r < 4; ++r) {
    int k = kb + ty + r*8;
    tile[ty + r*8][tx] = k2[(size_t)k*256 + nb + tx];
  }
  __syncthreads();
#pragma unroll
  for (int r = 0; r < 4; ++r) {
    int n = nb + ty + r*8;
    k2T[(size_t)n*20736 + kb + tx] = f2bf(tile[tx][ty + r*8]);
  }
}

// ------------------------------------------------------------------
// conv2 implicit GEMM: bf16 MFMA 16x16x32, BM=128 BN=64 BK=64, 4 waves,
// 2-buffer LDS + XOR swizzle, split-K x2 (blockIdx.z), f32 partials.
__global__ __launch_bounds__(256) void conv2_mfma(
    const USH* __restrict__ h, const USH* __restrict__ k2T,
    float* __restrict__ up)
{
  __shared__ __align__(16) USH Asm[2][128*64];
  __shared__ __align__(16) USH Bsm[2][64*64];
  int t = threadIdx.x;
  int mb = blockIdx.x, nb = blockIdx.y, ksl = blockIdx.z;

  int sg = (((t&7) ^ ((t>>3)&7)) << 3);   // pre-swizzled source group

  int arow_off[4];
#pragma unroll
  for (int i = 0; i < 4; ++i) {
    int row = (t>>3) + i*32;
    int m = mb*128 + row;
    int bb = m/36, r = m - bb*36;
    int oy = r/6, ox = r - oy*6;
    arow_off[i] = bb*102400 + oy*10240 + ox*512 + sg;
  }
  int brow_off[2];
#pragma unroll
  for (int i = 0; i < 2; ++i) {
    int nl = (t>>3) + i*32;
    brow_off[i] = (nb*64 + nl)*20736 + sg;
  }

  int lane = t & 63;
  int wave = t >> 6;
  int wm = (wave>>1)*64, wn = (wave&1)*32;
  int fr = lane & 15, fq = lane >> 4;

  f32x4 acc[4][2];
#pragma unroll
  for (int i = 0; i < 4; ++i)
#pragma unroll
    for (int j = 0; j < 2; ++j)
#pragma unroll
      for (int r = 0; r < 4; ++r) acc[i][j][r] = 0.f;

  int rg0 = (((0*4 + fq) ^ (fr&7)) << 3);
  int rg1 = (((1*4 + fq) ^ (fr&7)) << 3);

#define STAGE(buf, kt) do {                                            \
    int j_ = (kt) >> 2;                                                \
    int cin0_ = ((kt) & 3) << 6;                                       \
    int dy_ = j_/9, dx_ = j_ - dy_*9;                                  \
    int koff_ = (dy_*20 + dx_)*256 + cin0_;                            \
    USH* Ad_ = &Asm[buf][(t>>6)*512];                                  \
    USH* Bd_ = &Bsm[buf][(t>>6)*512];                                  \
    _Pragma("unroll")                                                  \
    for (int i_ = 0; i_ < 4; ++i_) gll16(h + arow_off[i_] + koff_, Ad_ + i_*2048); \
    _Pragma("unroll")                                                  \
    for (int i_ = 0; i_ < 2; ++i_) gll16(k2T + brow_off[i_] + (kt)*64, Bd_ + i_*2048); \
  } while(0)

  const int k0 = ksl*162, kend = k0 + 162;
  STAGE(0, k0);
  __syncthreads();

  int cur = 0;
  for (int kt = k0; kt < kend; ++kt) {
    if (kt + 1 < kend) STAGE(cur^1, kt+1);

    bf16x8 af[4][2], bg[2][2];
#pragma unroll
    for (int mf = 0; mf < 4; ++mf) {
      af[mf][0] = *(const bf16x8*)&Asm[cur][(wm + mf*16 + fr)*64 + rg0];
      af[mf][1] = *(const bf16x8*)&Asm[cur][(wm + mf*16 + fr)*64 + rg1];
    }
#pragma unroll
    for (int nf = 0; nf < 2; ++nf) {
      bg[nf][0] = *(const bf16x8*)&Bsm[cur][(wn + nf*16 + fr)*64 + rg0];
      bg[nf][1] = *(const bf16x8*)&Bsm[cur][(wn + nf*16 + fr)*64 + rg1];
    }
#pragma unroll
    for (int mf = 0; mf < 4; ++mf)
#pragma unroll
      for (int nf = 0; nf < 2; ++nf) {
        acc[mf][nf] = __builtin_amdgcn_mfma_f32_16x16x32_bf16(af[mf][0], bg[nf][0], acc[mf][nf], 0,0,0);
        acc[mf][nf] = __builtin_amdgcn_mfma_f32_16x16x32_bf16(af[mf][1], bg[nf][1], acc[mf][nf], 0,0,0);
      }
    __syncthreads();
    cur ^= 1;
  }
#undef STAGE

  float* dst = up + (size_t)ksl*4718592;
#pragma unroll
  for (int mf = 0; mf < 4; ++mf)
#pragma unroll
    for (int nf = 0; nf < 2; ++nf) {
      int n = nb*64 + wn + nf*16 + fr;
#pragma unroll
      for (int r = 0; r < 4; ++r) {
        int m = mb*128 + wm + mf*16 + fq*4 + r;
        dst[(size_t)m*256 + n] = acc[mf][nf][r];
      }
    }
}

// ------------------------------------------------------------------
// u = up[0] + up[1] + bias  (f32x4 over 18432x256)
__global__ __launch_bounds__(256) void reduce_u(
    const float* __restrict__ up, const float* __restrict__ b2, float* __restrict__ u)
{
  int i = blockIdx.x*256 + threadIdx.x;   // quad index
  f32x4 a = *(const f32x4*)&up[(size_t)i*4];
  f32x4 b = *(const f32x4*)&up[4718592ull + (size_t)i*4];
  int n0 = (i*4) & 255;
  f32x4 o;
#pragma unroll
  for (int j = 0; j < 4; ++j) o[j] = a[j] + b[j] + b2[n0 + j];
  *(f32x4*)&u[(size_t)i*4] = o;
}

// ------------------------------------------------------------------
// uT[col][b] = u[b][col]  (9216 x 512 f32), 32x32 padded-LDS transpose
__global__ __launch_bounds__(256) void tr_u(const float* __restrict__ u, float* __restrict__ uT)
{
  __shared__ float tile[32][33];
  int cb = blockIdx.x*32, bb = blockIdx.y*32;
  int tx = threadIdx.x & 31, ty = threadIdx.x >> 5;
#pragma unroll
  for (int r = 0; r < 4; ++r)
    tile[ty + r*8][tx] = u[(size_t)(bb + ty + r*8)*9216 + cb + tx];
  __syncthreads();
#pragma unroll
  for (int r = 0; r < 4; ++r)
    uT[(size_t)(cb + ty + r*8)*512 + bb + tx] = tile[tx][ty + r*8];
}

// ------------------------------------------------------------------
// Routing with u_hat recompute, v3: 2 b's per lane (w-load amortized x2,
// 32 FMA per 32B load-pair), reg headroom via launch_bounds(256,3) for
// compiler software-pipelining (round-8 was VGPR=72 load-serialized).
// Grid (16 b-chunks x 32 n-chunks); block 256 = 16 streams x 16 s-lanes.
// PASS1: acc += uhat. PASS2: softmax(uhat.vin) weighted accum
// (iter-3 logits = uhat.(v1+v2), so the same kernel serves pass 3 with vsum).
template<int PASS>
__global__ __launch_bounds__(256, 3) void route_recomp(
    const float* __restrict__ uT, const float* __restrict__ w,
    const float* __restrict__ vin, float* __restrict__ partR)
{
  int b0 = blockIdx.x*32, nbase = blockIdx.y*36;
  int t = threadIdx.x;
  int lane = t & 63, wv = t >> 6;
  int grp = lane >> 4, s = lane & 15;
  int stream = wv*4 + grp;
  bool act = s < 10;
  int sw = act ? s : 0;
  int bl0 = stream*2;                 // two local b's: bl0, bl0+1

  __shared__ float u_lds[2][32][12];  // [buf][b_local][p], 16B-aligned rows

  float vr0[16], vr1[16];
  if (PASS >= 2) {
    const float* vp0 = vin + (size_t)(b0+bl0)*160 + sw*16;
#pragma unroll
    for (int d = 0; d < 16; ++d) {
      vr0[d] = act ? vp0[d]       : 0.f;
      vr1[d] = act ? vp0[d + 160] : 0.f;
    }
  }
  float acc0[16], acc1[16];
#pragma unroll
  for (int d = 0; d < 16; ++d) { acc0[d] = 0.f; acc1[d] = 0.f; }

  // stage ni=0: thread t loads uT[(nbase*8 + p)][b0 + bl], p=t>>5, bl=t&31
  u_lds[0][t&31][t>>5] = uT[(size_t)(nbase*8 + (t>>5))*512 + b0 + (t&31)];
  __syncthreads();

  int cur = 0;
  for (int ni = 0; ni < 36; ++ni) {
    if (ni + 1 < 36)
      u_lds[cur^1][t&31][t>>5] =
          uT[(size_t)((nbase+ni+1)*8 + (t>>5))*512 + b0 + (t&31)];

    f32x4 u00 = *(const f32x4*)&u_lds[cur][bl0][0];
    f32x4 u01 = *(const f32x4*)&u_lds[cur][bl0][4];
    f32x4 u10 = *(const f32x4*)&u_lds[cur][bl0+1][0];
    f32x4 u11 = *(const f32x4*)&u_lds[cur][bl0+1][4];

    const f32x4* wp = (const f32x4*)(w + (size_t)(nbase+ni)*1280 + sw*128);
    float uh0[16], uh1[16];
#pragma unroll
    for (int d = 0; d < 16; ++d) {
      f32x4 wa = wp[2*d];
      f32x4 wb = wp[2*d+1];
      uh0[d] = wa[0]*u00[0]+wa[1]*u00[1]+wa[2]*u00[2]+wa[3]*u00[3]
             + wb[0]*u01[0]+wb[1]*u01[1]+wb[2]*u01[2]+wb[3]*u01[3];
      uh1[d] = wa[0]*u10[0]+wa[1]*u10[1]+wa[2]*u10[2]+wa[3]*u10[3]
             + wb[0]*u11[0]+wb[1]*u11[1]+wb[2]*u11[2]+wb[3]*u11[3];
    }

    if (PASS == 1) {
#pragma unroll
      for (int d = 0; d < 16; ++d) { acc0[d] += uh0[d]; acc1[d] += uh1[d]; }
    } else {
      float dot0 = 0.f, dot1 = 0.f;
#pragma unroll
      for (int d = 0; d < 16; ++d) { dot0 += uh0[d]*vr0[d]; dot1 += uh1[d]*vr1[d]; }
      float lg0 = act ? dot0 : -1e30f;
      float lg1 = act ? dot1 : -1e30f;
      float mx0 = lg0, mx1 = lg1;
      mx0 = fmaxf(mx0, __shfl_xor(mx0, 1, 16));
      mx1 = fmaxf(mx1, __shfl_xor(mx1, 1, 16));
      mx0 = fmaxf(mx0, __shfl_xor(mx0, 2, 16));
      mx1 = fmaxf(mx1, __shfl_xor(mx1, 2, 16));
      mx0 = fmaxf(mx0, __shfl_xor(mx0, 4, 16));
      mx1 = fmaxf(mx1, __shfl_xor(mx1, 4, 16));
      mx0 = fmaxf(mx0, __shfl_xor(mx0, 8, 16));
      mx1 = fmaxf(mx1, __shfl_xor(mx1, 8, 16));
      float e0 = __expf(lg0 - mx0);
      float e1 = __expf(lg1 - mx1);
      float sm0 = e0, sm1 = e1;
      sm0 += __shfl_xor(sm0, 1, 16);
      sm1 += __shfl_xor(sm1, 1, 16);
      sm0 += __shfl_xor(sm0, 2, 16);
      sm1 += __shfl_xor(sm1, 2, 16);
      sm0 += __shfl_xor(sm0, 4, 16);
      sm1 += __shfl_xor(sm1, 4, 16);
      sm0 += __shfl_xor(sm0, 8, 16);
      sm1 += __shfl_xor(sm1, 8, 16);
      float c0 = e0 / sm0;
      float c1 = e1 / sm1;
#pragma unroll
      for (int d = 0; d < 16; ++d) { acc0[d] += c0*uh0[d]; acc1[d] += c1*uh1[d]; }
    }
    __syncthreads();
    cur ^= 1;
  }

  if (act) {
    float* pp = &partR[((size_t)blockIdx.y*512 + b0 + bl0)*160 + s*16];
#pragma unroll
    for (int d = 0; d < 16; ++d) { pp[d] = acc0[d]; pp[d + 160] = acc1[d]; }
  }
}

// ------------------------------------------------------------------
// squash over 32 n-chunk partials.
// PASS1: scale 0.1, vout=v1. PASS2: vout=v2, vext=v1+v2. PASS3: vout=v3, vext=out.
template<int PASS>
__global__ __launch_bounds__(192) void squash_part(const float* __restrict__ partR,
    const float* __restrict__ vprev, float* __restrict__ vout, float* __restrict__ vext)
{
  int b = blockIdx.x, t = threadIdx.x;
  if (t < 160) {
    float sv = 0.f;
#pragma unroll
    for (int nc = 0; nc < 32; ++nc) sv += partR[((size_t)nc*512 + b)*160 + t];
    if (PASS == 1) sv *= 0.1f;
    float n2 = sv*sv;
    n2 += __shfl_xor(n2, 1, 16);
    n2 += __shfl_xor(n2, 2, 16);
    n2 += __shfl_xor(n2, 4, 16);
    n2 += __shfl_xor(n2, 8, 16);
    float nrm = sqrtf(n2);
    float o = (n2/(1.f + n2)) * sv / (nrm + 1e-7f);
    vout[b*160 + t] = o;
    if (PASS == 2) vext[b*160 + t] = vprev[b*160 + t] + o;  // vsum for iter-3 logits
    if (PASS == 3) vext[b*160 + t] = o;                      // out[0:81920] = v
  }
}

// ------------------------------------------------------------------
// decoder
__global__ __launch_bounds__(512) void d1_kernel(const float* __restrict__ v3,
    const int* __restrict__ labels, const float* __restrict__ w,
    const float* __restrict__ bias, float* __restrict__ r1)
{
  int b = blockIdx.x; int j = threadIdx.x;
  int lb = labels[b];
  float acc = bias[j];
#pragma unroll
  for (int d = 0; d < 16; ++d)
    acc += v3[b*160 + lb*16 + d] * w[(lb*16 + d)*512 + j];
  r1[(size_t)b*512 + j] = acc > 0.f ? acc : 0.f;
}

__global__ __launch_bounds__(256) void d2_kernel(const float* __restrict__ a,
    const float* __restrict__ w, const float* __restrict__ bias, float* __restrict__ o)
{
  int j = blockIdx.x*256 + threadIdx.x;
  int b0 = blockIdx.y*8;
  __shared__ float as[8*512];
  for (int i = threadIdx.x; i < 8*512; i += 256) as[i] = a[(size_t)(b0 + (i>>9))*512 + (i&511)];
  __syncthreads();
  float acc[8];
  float bs = bias[j];
#pragma unroll
  for (int i = 0; i < 8; ++i) acc[i] = bs;
  for (int k = 0; k < 512; ++k) {
    float wv = w[(size_t)k*1024 + j];
#pragma unroll
    for (int i = 0; i < 8; ++i) acc[i] += as[i*512 + k]*wv;
  }
#pragma unroll
  for (int i = 0; i < 8; ++i)
    o[(size_t)(b0+i)*1024 + j] = acc[i] > 0.f ? acc[i] : 0.f;
}

__global__ __launch_bounds__(256) void d3_kernel(const float* __restrict__ a,
    const float* __restrict__ w, const float* __restrict__ bias, float* __restrict__ o)
{
  int j = blockIdx.x*256 + threadIdx.x;
  int b0 = blockIdx.y*8;
  __shared__ float as[8*1024];
  for (int i = threadIdx.x; i < 8*1024; i += 256) as[i] = a[(size_t)(b0 + (i>>10))*1024 + (i&1023)];
  __syncthreads();
  if (j < 784) {
    float acc[8];
    float bs = bias[j];
#pragma unroll
    for (int i = 0; i < 8; ++i) acc[i] = bs;
    for (int k = 0; k < 1024; ++k) {
      float wv = w[(size_t)k*784 + j];
#pragma unroll
      for (int i = 0; i < 8; ++i) acc[i] += as[i*1024 + k]*wv;
    }
#pragma unroll
    for (int i = 0; i < 8; ++i)
      o[(size_t)(b0+i)*784 + j] = 1.f/(1.f + __expf(-acc[i]));
  }
}

// ------------------------------------------------------------------
extern "C" void kernel_launch(void* const* d_in, const int* in_sizes, int n_in,
                              void* d_out, int out_size, void* d_ws, size_t ws_size,
                              hipStream_t stream)
{
  const float* x   = (const float*)d_in[0];
  const int*   lab = (const int*)  d_in[1];
  const float* k1  = (const float*)d_in[2];
  const float* b1  = (const float*)d_in[3];
  const float* k2  = (const float*)d_in[4];
  const float* b2  = (const float*)d_in[5];
  const float* w   = (const float*)d_in[6];
  const float* d1w = (const float*)d_in[7];
  const float* d1b = (const float*)d_in[8];
  const float* d2w = (const float*)d_in[9];
  const float* d2b = (const float*)d_in[10];
  const float* d3w = (const float*)d_in[11];
  const float* d3b = (const float*)d_in[12];
  float* out = (float*)d_out;

  char* ws = (char*)d_ws;
  // layout (bytes):
  //   h    [0, 104857600)          bf16 conv1 out (dead after conv2)
  //   up   [104857600, 142606336)  conv2 partials (dead after reduce_u)
  //   uT   [104857600, 123731968)  overlays dead up after reduce_u (18.9 MB)
  //   u    [188743680, 207618048)
  //   k2T  [207618048, 218234880)  (dead after conv2; partR overlays: 10.49 MB)
  //   v/r  [218234880, ...)
  USH*   h     = (USH*)(ws + 0);
  float* up    = (float*)(ws + 104857600ull);
  float* uT    = (float*)(ws + 104857600ull);
  float* u     = (float*)(ws + 188743680ull);
  USH*   k2T   = (USH*)(ws + 207618048ull);
  float* partR = (float*)(ws + 207618048ull);
  float* v1    = (float*)(ws + 218234880ull);
  float* v2    = (float*)(ws + 218562560ull);
  float* v3    = (float*)(ws + 218890240ull);
  float* vsum  = (float*)(ws + 219217920ull);
  float* r1    = (float*)(ws + 219545600ull);
  float* r2    = (float*)(ws + 220594176ull);

  conv1_kernel<<<dim3(512,5), 256, 0, stream>>>(x, k1, b1, h);
  tr_k2<<<dim3(648,8), 256, 0, stream>>>(k2, k2T);
  conv2_mfma<<<dim3(144,4,2), 256, 0, stream>>>(h, k2T, up);
  reduce_u<<<4608, 256, 0, stream>>>(up, b2, u);
  tr_u<<<dim3(288,16), 256, 0, stream>>>(u, uT);   // up region dead; uT overlays it

  route_recomp<1><<<dim3(16,32), 256, 0, stream>>>(uT, w, nullptr, partR);
  squash_part<1><<<512, 192, 0, stream>>>(partR, nullptr, v1, nullptr);
  route_recomp<2><<<dim3(16,32), 256, 0, stream>>>(uT, w, v1, partR);
  squash_part<2><<<512, 192, 0, stream>>>(partR, v1, v2, vsum);
  route_recomp<2><<<dim3(16,32), 256, 0, stream>>>(uT, w, vsum, partR);
  squash_part<3><<<512, 192, 0, stream>>>(partR, nullptr, v3, out);

  d1_kernel<<<512, 512, 0, stream>>>(v3, lab, d1w, d1b, r1);
  d2_kernel<<<dim3(4,64), 256, 0, stream>>>(r1, d2w, d2b, r2);
  d3_kernel<<<dim3(4,64), 256, 0, stream>>>(r2, d3w, d3b, out + 81920);
}

// Round 10
// 712.761 us; speedup vs baseline: 2.3684x; 1.7252x over previous
//
#include <hip/hip_runtime.h>

#define USH unsigned short

__device__ inline float bf2f(USH u){ return __uint_as_float(((unsigned)u)<<16); }
__device__ inline USH f2bf(float f){
  unsigned u = __float_as_uint(f);
  return (USH)((u + 0x7FFFu + ((u>>16)&1u))>>16);
}

typedef __attribute__((ext_vector_type(8))) short bf16x8;
typedef __attribute__((ext_vector_type(4))) float f32x4;

__device__ inline void gll16(const USH* g, USH* l){
  __builtin_amdgcn_global_load_lds((const __attribute__((address_space(1))) void*)g,
                                   (__attribute__((address_space(3))) void*)l, 16, 0, 0);
}

// ------------------------------------------------------------------
// im2col for conv1: x(512,28,28) f32 -> xcol[b*400 + y*20 + x][96] bf16
// (k = dy*9+dx for k<81, zero-pad 81..95)
__global__ __launch_bounds__(256) void im2col_k(
    const float* __restrict__ x, USH* __restrict__ xcol)
{
  int b = blockIdx.x, t = threadIdx.x;
  __shared__ float xs[784];
  for (int i = t; i < 784; i += 256) xs[i] = x[b*784 + i];
  __syncthreads();
  USH* dst = xcol + (size_t)b*38400;
  for (int idx = t; idx < 38400; idx += 256) {
    int sp = idx / 96, k = idx - sp*96;
    int y = sp / 20, xx = sp - y*20;
    USH v = 0;
    if (k < 81) {
      int dy = k / 9, dx = k - dy*9;
      v = f2bf(xs[(y+dy)*28 + xx + dx]);
    }
    dst[idx] = v;
  }
}

// k1 (81,256) f32 -> k1T (256,96) bf16 zero-padded
__global__ __launch_bounds__(256) void tr_k1(const float* __restrict__ k1, USH* __restrict__ k1T)
{
  int n = threadIdx.x;
  for (int k = 0; k < 96; ++k)
    k1T[n*96 + k] = (k < 81) ? f2bf(k1[k*256 + n]) : (USH)0;
}

// ------------------------------------------------------------------
// conv1 as GEMM: C[204800 x 256] = xcol[204800 x 96] @ k1T^T, +bias, relu -> h bf16
// BM=64, BN=256, K=96 (3 MFMA k-steps), 4 waves (wave tile 64x64), NO LDS:
// fragments loaded direct from global (k1T is L1/L2-resident, xcol L2).
__global__ __launch_bounds__(256) void gemm1(
    const USH* __restrict__ xcol, const USH* __restrict__ k1T,
    const float* __restrict__ b1, USH* __restrict__ h)
{
  int t = threadIdx.x;
  int m0 = blockIdx.x * 64;
  int lane = t & 63, wave = t >> 6;
  int wn = wave * 64;
  int fr = lane & 15, fq = lane >> 4;

  f32x4 acc[4][4];
#pragma unroll
  for (int i = 0; i < 4; ++i)
#pragma unroll
    for (int j = 0; j < 4; ++j)
#pragma unroll
      for (int r = 0; r < 4; ++r) acc[i][j][r] = 0.f;

#pragma unroll
  for (int kt = 0; kt < 3; ++kt) {
    int kc = kt*32 + fq*8;
    bf16x8 af[4], bg[4];
#pragma unroll
    for (int mf = 0; mf < 4; ++mf)
      af[mf] = *(const bf16x8*)&xcol[(size_t)(m0 + mf*16 + fr)*96 + kc];
#pragma unroll
    for (int nf = 0; nf < 4; ++nf)
      bg[nf] = *(const bf16x8*)&k1T[(size_t)(wn + nf*16 + fr)*96 + kc];
#pragma unroll
    for (int mf = 0; mf < 4; ++mf)
#pragma unroll
      for (int nf = 0; nf < 4; ++nf)
        acc[mf][nf] = __builtin_amdgcn_mfma_f32_16x16x32_bf16(af[mf], bg[nf], acc[mf][nf], 0,0,0);
  }

#pragma unroll
  for (int mf = 0; mf < 4; ++mf)
#pragma unroll
    for (int nf = 0; nf < 4; ++nf) {
      int n = wn + nf*16 + fr;
      float bias = b1[n];
#pragma unroll
      for (int r = 0; r < 4; ++r) {
        int m = m0 + mf*16 + fq*4 + r;
        float v = acc[mf][nf][r] + bias;
        h[(size_t)m*256 + n] = f2bf(v > 0.f ? v : 0.f);
      }
    }
}

// ------------------------------------------------------------------
// k2 (20736,256) f32 -> k2T (256,20736) bf16
__global__ __launch_bounds__(256) void tr_k2(const float* __restrict__ k2, USH* __restrict__ k2T)
{
  __shared__ float tile[32][33];
  int kb = blockIdx.x*32, nb = blockIdx.y*32;
  int tx = threadIdx.x & 31, ty = threadIdx.x >> 5;
#pragma unroll
  for (int r = 0; r < 4; ++r) {
    int k = kb + ty + r*8;
    tile[ty + r*8][tx] = k2[(size_t)k*256 + nb + tx];
  }
  __syncthreads();
#pragma unroll
  for (int r = 0; r < 4; ++r) {
    int n = nb + ty + r*8;
    k2T[(size_t)n*20736 + kb + tx] = f2bf(tile[tx][ty + r*8]);
  }
}

// ------------------------------------------------------------------
// conv2 implicit GEMM: bf16 MFMA 16x16x32, BM=128 BN=64 BK=64, 4 waves,
// 2-buffer LDS + XOR swizzle, split-K x2 (blockIdx.z), f32 partials.
__global__ __launch_bounds__(256) void conv2_mfma(
    const USH* __restrict__ h, const USH* __restrict__ k2T,
    float* __restrict__ up)
{
  __shared__ __align__(16) USH Asm[2][128*64];
  __shared__ __align__(16) USH Bsm[2][64*64];
  int t = threadIdx.x;
  int mb = blockIdx.x, nb = blockIdx.y, ksl = blockIdx.z;

  int sg = (((t&7) ^ ((t>>3)&7)) << 3);   // pre-swizzled source group

  int arow_off[4];
#pragma unroll
  for (int i = 0; i < 4; ++i) {
    int row = (t>>3) + i*32;
    int m = mb*128 + row;
    int bb = m/36, r = m - bb*36;
    int oy = r/6, ox = r - oy*6;
    arow_off[i] = bb*102400 + oy*10240 + ox*512 + sg;
  }
  int brow_off[2];
#pragma unroll
  for (int i = 0; i < 2; ++i) {
    int nl = (t>>3) + i*32;
    brow_off[i] = (nb*64 + nl)*20736 + sg;
  }

  int lane = t & 63;
  int wave = t >> 6;
  int wm = (wave>>1)*64, wn = (wave&1)*32;
  int fr = lane & 15, fq = lane >> 4;

  f32x4 acc[4][2];
#pragma unroll
  for (int i = 0; i < 4; ++i)
#pragma unroll
    for (int j = 0; j < 2; ++j)
#pragma unroll
      for (int r = 0; r < 4; ++r) acc[i][j][r] = 0.f;

  int rg0 = (((0*4 + fq) ^ (fr&7)) << 3);
  int rg1 = (((1*4 + fq) ^ (fr&7)) << 3);

#define STAGE(buf, kt) do {                                            \
    int j_ = (kt) >> 2;                                                \
    int cin0_ = ((kt) & 3) << 6;                                       \
    int dy_ = j_/9, dx_ = j_ - dy_*9;                                  \
    int koff_ = (dy_*20 + dx_)*256 + cin0_;                            \
    USH* Ad_ = &Asm[buf][(t>>6)*512];                                  \
    USH* Bd_ = &Bsm[buf][(t>>6)*512];                                  \
    _Pragma("unroll")                                                  \
    for (int i_ = 0; i_ < 4; ++i_) gll16(h + arow_off[i_] + koff_, Ad_ + i_*2048); \
    _Pragma("unroll")                                                  \
    for (int i_ = 0; i_ < 2; ++i_) gll16(k2T + brow_off[i_] + (kt)*64, Bd_ + i_*2048); \
  } while(0)

  const int k0 = ksl*162, kend = k0 + 162;
  STAGE(0, k0);
  __syncthreads();

  int cur = 0;
  for (int kt = k0; kt < kend; ++kt) {
    if (kt + 1 < kend) STAGE(cur^1, kt+1);

    bf16x8 af[4][2], bg[2][2];
#pragma unroll
    for (int mf = 0; mf < 4; ++mf) {
      af[mf][0] = *(const bf16x8*)&Asm[cur][(wm + mf*16 + fr)*64 + rg0];
      af[mf][1] = *(const bf16x8*)&Asm[cur][(wm + mf*16 + fr)*64 + rg1];
    }
#pragma unroll
    for (int nf = 0; nf < 2; ++nf) {
      bg[nf][0] = *(const bf16x8*)&Bsm[cur][(wn + nf*16 + fr)*64 + rg0];
      bg[nf][1] = *(const bf16x8*)&Bsm[cur][(wn + nf*16 + fr)*64 + rg1];
    }
#pragma unroll
    for (int mf = 0; mf < 4; ++mf)
#pragma unroll
      for (int nf = 0; nf < 2; ++nf) {
        acc[mf][nf] = __builtin_amdgcn_mfma_f32_16x16x32_bf16(af[mf][0], bg[nf][0], acc[mf][nf], 0,0,0);
        acc[mf][nf] = __builtin_amdgcn_mfma_f32_16x16x32_bf16(af[mf][1], bg[nf][1], acc[mf][nf], 0,0,0);
      }
    __syncthreads();
    cur ^= 1;
  }
#undef STAGE

  float* dst = up + (size_t)ksl*4718592;
#pragma unroll
  for (int mf = 0; mf < 4; ++mf)
#pragma unroll
    for (int nf = 0; nf < 2; ++nf) {
      int n = nb*64 + wn + nf*16 + fr;
#pragma unroll
      for (int r = 0; r < 4; ++r) {
        int m = mb*128 + wm + mf*16 + fq*4 + r;
        dst[(size_t)m*256 + n] = acc[mf][nf][r];
      }
    }
}

// ------------------------------------------------------------------
// u = up[0] + up[1] + bias  (f32x4 over 18432x256)
__global__ __launch_bounds__(256) void reduce_u(
    const float* __restrict__ up, const float* __restrict__ b2, float* __restrict__ u)
{
  int i = blockIdx.x*256 + threadIdx.x;
  f32x4 a = *(const f32x4*)&up[(size_t)i*4];
  f32x4 b = *(const f32x4*)&up[4718592ull + (size_t)i*4];
  int n0 = (i*4) & 255;
  f32x4 o;
#pragma unroll
  for (int j = 0; j < 4; ++j) o[j] = a[j] + b[j] + b2[n0 + j];
  *(f32x4*)&u[(size_t)i*4] = o;
}

// ------------------------------------------------------------------
// Wsum[n*8+p][sd] = w[n, sd>>4, sd&15, p]   (9216 x 160 f32)
__global__ __launch_bounds__(192) void wsum_tr(const float* __restrict__ w,
    float* __restrict__ Ws)
{
  int n = blockIdx.x, t = threadIdx.x;
  __shared__ float wn[1280];
  for (int i = t; i < 1280; i += 192) wn[i] = w[n*1280 + i];
  __syncthreads();
  if (t < 160) {
#pragma unroll
    for (int p = 0; p < 8; ++p)
      Ws[((size_t)n*8 + p)*160 + t] = wn[(t>>4)*128 + (t&15)*8 + p];
  }
}

// ------------------------------------------------------------------
// s1 partials: part[ks][b][160] = u[b, k0:k0+288] @ Ws[k0:k0+288, :]
__global__ __launch_bounds__(192) void p1gemm(const float* __restrict__ u,
    const float* __restrict__ Ws, float* __restrict__ part)
{
  int b0 = blockIdx.x*32, k0 = blockIdx.y*288;
  int t = threadIdx.x;
  __shared__ float usm[288*36];
  for (int i = t; i < 288*32; i += 192) {
    int bl = i/288, kk = i - bl*288;
    usm[kk*36 + bl] = u[(size_t)(b0+bl)*9216 + k0 + kk];
  }
  __syncthreads();
  if (t < 160) {
    const float* wp = Ws + (size_t)k0*160 + t;
#pragma unroll 1
    for (int half = 0; half < 2; ++half) {
      float acc[16];
#pragma unroll
      for (int i = 0; i < 16; ++i) acc[i] = 0.f;
      for (int kk = 0; kk < 288; ++kk) {
        float wv = wp[(size_t)kk*160];
        const f32x4* ub = (const f32x4*)&usm[kk*36 + half*16];
        f32x4 u0 = ub[0], u1 = ub[1], u2 = ub[2], u3 = ub[3];
#pragma unroll
        for (int i = 0; i < 4; ++i) {
          acc[i]    += u0[i]*wv;
          acc[4+i]  += u1[i]*wv;
          acc[8+i]  += u2[i]*wv;
          acc[12+i] += u3[i]*wv;
        }
      }
      float* pp = &part[((size_t)blockIdx.y*512 + b0 + half*16)*160 + t];
#pragma unroll
      for (int i = 0; i < 16; ++i) pp[(size_t)i*160] = acc[i];
    }
  }
}

// ------------------------------------------------------------------
// v1 = squash(0.1 * sum_ks part[ks][b][:])
__global__ __launch_bounds__(192) void squash1(const float* __restrict__ part,
    float* __restrict__ vout)
{
  int b = blockIdx.x, t = threadIdx.x;
  if (t < 160) {
    float sv = 0.f;
    for (int ks = 0; ks < 32; ++ks) sv += part[((size_t)ks*512 + b)*160 + t];
    sv *= 0.1f;
    float n2 = sv*sv;
    n2 += __shfl_xor(n2, 1, 16);
    n2 += __shfl_xor(n2, 2, 16);
    n2 += __shfl_xor(n2, 4, 16);
    n2 += __shfl_xor(n2, 8, 16);
    float nrm = sqrtf(n2);
    float o = (n2/(1.f + n2)) * sv / (nrm + 1e-7f);
    vout[b*160 + t] = o;
  }
}

// ------------------------------------------------------------------
// u_hat[b,n,s,d] = sum_p w[n,s,d,p]*u[b,n,p]  -> bf16 [512][1152][160]
// block = (n, 64 b's); w staged at stride 65 (conflict-free).
__global__ __launch_bounds__(256) void uhat_kernel(
    const float* __restrict__ u, const float* __restrict__ w, USH* __restrict__ uh)
{
  int n = blockIdx.x, b0 = blockIdx.y*64;
  int t = threadIdx.x;
  __shared__ float wsm[20*65];
  __shared__ float usm[512];
  for (int i = t; i < 1280; i += 256) wsm[(i>>6)*65 + (i&63)] = w[n*1280 + i];
  for (int i = t; i < 512; i += 256) {
    int bl = i>>3, p = i&7;
    usm[i] = u[(size_t)(b0+bl)*9216 + n*8 + p];
  }
  __syncthreads();
  for (int v = t; v < 1280; v += 256) {     // 64 b x 20 octs
    int bl = v/20, oct = v - bl*20;
    const float* upt = &usm[bl*8];
    bf16x8 pk;
#pragma unroll
    for (int j = 0; j < 8; ++j) {
      const float* wp = &wsm[oct*65 + j*8];
      float a = 0.f;
#pragma unroll
      for (int p = 0; p < 8; ++p) a += wp[p]*upt[p];
      pk[j] = (short)f2bf(a);
    }
    *(bf16x8*)&uh[(size_t)(b0+bl)*184320 + n*160 + oct*8] = pk;
  }
}

// ------------------------------------------------------------------
// Routing pass partial: block (b, nc) handles 288 n's (16 streams x 18).
template<int PASS>
__global__ __launch_bounds__(256) void route_part(
    const USH* __restrict__ uh, const float* __restrict__ vin,
    float* __restrict__ L, float* __restrict__ partR)
{
  int b = blockIdx.x, nc = blockIdx.y;
  int t = threadIdx.x;
  int lane = t & 63, w = t >> 6;
  int grp = lane >> 4, s = lane & 15;
  int stream = w*4 + grp;
  bool act = s < 10;

  float vr[16];
  {
    const float* vp = vin + b*160 + s*16;
#pragma unroll
    for (int d = 0; d < 16; ++d) vr[d] = act ? vp[d] : 0.f;
  }
  float acc[16];
#pragma unroll
  for (int d = 0; d < 16; ++d) acc[d] = 0.f;

  const USH* ub = uh + (size_t)b*184320;
  int nbase = nc*288 + stream*18;
  for (int ni = 0; ni < 18; ++ni) {
    int n = nbase + ni;
    float uv[16];
    if (act) {
      const USH* upt = ub + n*160 + s*16;
      bf16x8 p0 = *(const bf16x8*)upt;
      bf16x8 p1 = *(const bf16x8*)(upt + 8);
#pragma unroll
      for (int d = 0; d < 8; ++d) { uv[d] = bf2f((USH)p0[d]); uv[8+d] = bf2f((USH)p1[d]); }
    } else {
#pragma unroll
      for (int d = 0; d < 16; ++d) uv[d] = 0.f;
    }

    float dot = 0.f;
#pragma unroll
    for (int d = 0; d < 16; ++d) dot += uv[d]*vr[d];
    float lg;
    if (PASS == 2) {
      lg = dot;
      if (act) L[((size_t)b*1152 + n)*10 + s] = dot;
    } else {
      lg = act ? (L[((size_t)b*1152 + n)*10 + s] + dot) : 0.f;
    }
    if (!act) lg = -1e30f;
    float mx = lg;
    mx = fmaxf(mx, __shfl_xor(mx, 1, 16));
    mx = fmaxf(mx, __shfl_xor(mx, 2, 16));
    mx = fmaxf(mx, __shfl_xor(mx, 4, 16));
    mx = fmaxf(mx, __shfl_xor(mx, 8, 16));
    float e = __expf(lg - mx);
    float sum = e;
    sum += __shfl_xor(sum, 1, 16);
    sum += __shfl_xor(sum, 2, 16);
    sum += __shfl_xor(sum, 4, 16);
    sum += __shfl_xor(sum, 8, 16);
    float c = e / sum;
#pragma unroll
    for (int d = 0; d < 16; ++d) acc[d] += c*uv[d];
  }

  __shared__ float red[16][168];
  if (act) {
#pragma unroll
    for (int d = 0; d < 16; ++d) red[stream][s*16 + d] = acc[d];
  }
  __syncthreads();
  if (t < 160) {
    float sv = 0.f;
#pragma unroll
    for (int k = 0; k < 16; ++k) sv += red[k][t];
    partR[((size_t)nc*512 + b)*160 + t] = sv;
  }
}

// ------------------------------------------------------------------
// squash over 4 n-chunk partials
template<int PASS>
__global__ __launch_bounds__(192) void squash_part(const float* __restrict__ partR,
    float* __restrict__ vout, float* __restrict__ vext)
{
  int b = blockIdx.x, t = threadIdx.x;
  if (t < 160) {
    float sv = 0.f;
#pragma unroll
    for (int nc = 0; nc < 4; ++nc) sv += partR[((size_t)nc*512 + b)*160 + t];
    float n2 = sv*sv;
    n2 += __shfl_xor(n2, 1, 16);
    n2 += __shfl_xor(n2, 2, 16);
    n2 += __shfl_xor(n2, 4, 16);
    n2 += __shfl_xor(n2, 8, 16);
    float nrm = sqrtf(n2);
    float o = (n2/(1.f + n2)) * sv / (nrm + 1e-7f);
    vout[b*160 + t] = o;
    if (PASS == 3) vext[b*160 + t] = o;
  }
}

// ------------------------------------------------------------------
// decoder
__global__ __launch_bounds__(512) void d1_kernel(const float* __restrict__ v3,
    const int* __restrict__ labels, const float* __restrict__ w,
    const float* __restrict__ bias, float* __restrict__ r1)
{
  int b = blockIdx.x; int j = threadIdx.x;
  int lb = labels[b];
  float acc = bias[j];
#pragma unroll
  for (int d = 0; d < 16; ++d)
    acc += v3[b*160 + lb*16 + d] * w[(lb*16 + d)*512 + j];
  r1[(size_t)b*512 + j] = acc > 0.f ? acc : 0.f;
}

__global__ __launch_bounds__(256) void d2_kernel(const float* __restrict__ a,
    const float* __restrict__ w, const float* __restrict__ bias, float* __restrict__ o)
{
  int j = blockIdx.x*256 + threadIdx.x;
  int b0 = blockIdx.y*4;
  __shared__ float as[4*512];
  for (int i = threadIdx.x; i < 4*512; i += 256) as[i] = a[(size_t)(b0 + (i>>9))*512 + (i&511)];
  __syncthreads();
  float acc[4];
  float bs = bias[j];
#pragma unroll
  for (int i = 0; i < 4; ++i) acc[i] = bs;
  for (int k = 0; k < 512; ++k) {
    float wv = w[(size_t)k*1024 + j];
#pragma unroll
    for (int i = 0; i < 4; ++i) acc[i] += as[i*512 + k]*wv;
  }
#pragma unroll
  for (int i = 0; i < 4; ++i)
    o[(size_t)(b0+i)*1024 + j] = acc[i] > 0.f ? acc[i] : 0.f;
}

__global__ __launch_bounds__(256) void d3_kernel(const float* __restrict__ a,
    const float* __restrict__ w, const float* __restrict__ bias, float* __restrict__ o)
{
  int j = blockIdx.x*256 + threadIdx.x;
  int b0 = blockIdx.y*4;
  __shared__ float as[4*1024];
  for (int i = threadIdx.x; i < 4*1024; i += 256) as[i] = a[(size_t)(b0 + (i>>10))*1024 + (i&1023)];
  __syncthreads();
  if (j < 784) {
    float acc[4];
    float bs = bias[j];
#pragma unroll
    for (int i = 0; i < 4; ++i) acc[i] = bs;
    for (int k = 0; k < 1024; ++k) {
      float wv = w[(size_t)k*784 + j];
#pragma unroll
      for (int i = 0; i < 4; ++i) acc[i] += as[i*1024 + k]*wv;
    }
#pragma unroll
    for (int i = 0; i < 4; ++i)
      o[(size_t)(b0+i)*784 + j] = 1.f/(1.f + __expf(-acc[i]));
  }
}

// ------------------------------------------------------------------
extern "C" void kernel_launch(void* const* d_in, const int* in_sizes, int n_in,
                              void* d_out, int out_size, void* d_ws, size_t ws_size,
                              hipStream_t stream)
{
  const float* x   = (const float*)d_in[0];
  const int*   lab = (const int*)  d_in[1];
  const float* k1  = (const float*)d_in[2];
  const float* b1  = (const float*)d_in[3];
  const float* k2  = (const float*)d_in[4];
  const float* b2  = (const float*)d_in[5];
  const float* w   = (const float*)d_in[6];
  const float* d1w = (const float*)d_in[7];
  const float* d1b = (const float*)d_in[8];
  const float* d2w = (const float*)d_in[9];
  const float* d2b = (const float*)d_in[10];
  const float* d3w = (const float*)d_in[11];
  const float* d3b = (const float*)d_in[12];
  float* out = (float*)d_out;

  char* ws = (char*)d_ws;
  // layout (bytes):
  //   uh   [0, 188743680)        bf16 [512][1152][160]
  //   h    overlays [0, 104857600)            (dead after conv2)
  //   up   [104857600, 142606336)  conv2 partials (dead after reduce_u; before uh)
  //   xcol [142606336, 181927936)  39.3 MB (live only conv1 phase, before uh)
  //   u    [188743680, 207618048)
  //   k2T  [207618048, 218234880)  (dead after conv2; p1 part + route partR overlay)
  //   L    [218234880, 241827840)  (Wsum overlays before route2)
  //   k1T  [241827840, 241926144)  48KB (live only conv1 phase)
  //   v/r  beyond 242155520
  USH*   uh    = (USH*)(ws + 0);
  USH*   h     = (USH*)(ws + 0);
  float* up    = (float*)(ws + 104857600ull);
  USH*   xcol  = (USH*)(ws + 142606336ull);
  float* u     = (float*)(ws + 188743680ull);
  USH*   k2T   = (USH*)(ws + 207618048ull);
  float* part  = (float*)(ws + 207618048ull);
  float* partR = (float*)(ws + 207618048ull);
  float* L     = (float*)(ws + 218234880ull);
  float* Wsum  = (float*)(ws + 218234880ull);
  USH*   k1T   = (USH*)(ws + 241827840ull);
  float* v1    = (float*)(ws + 242155520ull);
  float* v2    = (float*)(ws + 242483200ull);
  float* v3    = (float*)(ws + 242810880ull);
  float* r1    = (float*)(ws + 243138560ull);
  float* r2    = (float*)(ws + 244187136ull);

  im2col_k<<<512, 256, 0, stream>>>(x, xcol);
  tr_k1<<<1, 256, 0, stream>>>(k1, k1T);
  gemm1<<<3200, 256, 0, stream>>>(xcol, k1T, b1, h);

  tr_k2<<<dim3(648,8), 256, 0, stream>>>(k2, k2T);
  conv2_mfma<<<dim3(144,4,2), 256, 0, stream>>>(h, k2T, up);
  reduce_u<<<4608, 256, 0, stream>>>(up, b2, u);

  wsum_tr<<<1152, 192, 0, stream>>>(w, Wsum);
  p1gemm<<<dim3(16,32), 192, 0, stream>>>(u, Wsum, part);
  squash1<<<512, 192, 0, stream>>>(part, v1);

  uhat_kernel<<<dim3(1152,8), 256, 0, stream>>>(u, w, uh);

  route_part<2><<<dim3(512,4), 256, 0, stream>>>(uh, v1, L, partR);
  squash_part<2><<<512, 192, 0, stream>>>(partR, v2, nullptr);
  route_part<3><<<dim3(512,4), 256, 0, stream>>>(uh, v2, L, partR);
  squash_part<3><<<512, 192, 0, stream>>>(partR, v3, out);

  d1_kernel<<<512, 512, 0, stream>>>(v3, lab, d1w, d1b, r1);
  d2_kernel<<<dim3(4,128), 256, 0, stream>>>(r1, d2w, d2b, r2);
  d3_kernel<<<dim3(4,128), 256, 0, stream>>>(r2, d3w, d3b, out + 81920);
}